// Round 4
// baseline (107.322 us; speedup 1.0000x reference)
//
#include <hip/hip_runtime.h>

#define NAGENT 8192
#define NCELL 36
#define HIDDEN 128
#define CSTRIDE 37   // k2 LDS occ row stride (gcd(37,32)=1)
#define PWORDS 18    // packed row: 36 cells as 18 u32 (2 x u16)
#define NCHUNK 32
#define JCHUNK (NAGENT / NCHUNK)  // 256 js per block

// ---------------------------------------------------------------------------
// k1: pairwise occupancy histogram. Grid dim3(NCHUNK, 32).
// Block = 256 DISTINCT agents (tid = agent-in-group; 4 waves carry different
// agents), all waves scan the SAME j-chunk -> j address depends only on
// blockIdx/loop counter -> uniform -> scalar-cache s_load (zero LDS reads in
// the hot loop; R3 was LDS-pipe-bound on broadcast ds_read_b128).
// Counters are COL-MAJOR: cnt[cell*256 + tid] -> LDS bank = tid%32 for every
// cell -> guaranteed 2-way bank access (free, m136) for all ds_add atomics;
// R3's row-major layout scattered atomics over random banks (~5-way max-load).
// j==i masked explicitly (1 cmp/point) -> no self-pair subtraction needed and
// no dependence on where rounding lands the self cell.
// Epilogue: pack 2 cells/u32 (per-chunk counts <= 256), coalesced stores.
// ---------------------------------------------------------------------------
__global__ __launch_bounds__(256) void occ_hist_kernel(
    const float2* __restrict__ obs, unsigned* __restrict__ partial) {
  __shared__ unsigned cnt[NCELL * 256];  // 36.9 KB -> 4 blocks/CU
  const int tid = threadIdx.x;
#pragma unroll
  for (int c = 0; c < NCELL; ++c) cnt[c * 256 + tid] = 0u;  // bank tid%32
  __syncthreads();

  const int agent = blockIdx.y * 256 + tid;
  const float2 oi = obs[agent];
  const float cx = fmaf(oi.x, -2.0f, 3.0f);  // rx = xj*2 + (3 - 2*xi)
  const float cy = fmaf(oi.y, -2.0f, 3.0f);
  unsigned* myCol = &cnt[tid];

  const int jbase = blockIdx.x * JCHUNK;
  const float4* jp = (const float4*)obs + (jbase >> 1);

#pragma unroll 8
  for (int t = 0; t < JCHUNK / 2; ++t) {
    const float4 o2 = jp[t];  // uniform address -> s_load / L1 broadcast
    const int j0 = jbase + 2 * t;
    {
      const float rx = fmaf(o2.x, 2.0f, cx);
      const float ry = fmaf(o2.y, 2.0f, cy);
      if (rx >= 0.0f && rx < 6.0f && ry >= 0.0f && ry < 6.0f && agent != j0)
        atomicAdd(&myCol[((int)rx * 6 + (int)ry) << 8], 1u);
    }
    {
      const float rx = fmaf(o2.z, 2.0f, cx);
      const float ry = fmaf(o2.w, 2.0f, cy);
      if (rx >= 0.0f && rx < 6.0f && ry >= 0.0f && ry < 6.0f && agent != j0 + 1)
        atomicAdd(&myCol[((int)rx * 6 + (int)ry) << 8], 1u);
    }
  }
  __syncthreads();

  // pack 2 x u16 per u32 + plain coalesced stores (18 iterations)
  unsigned* gbase = partial +
      ((size_t)blockIdx.x * NAGENT + (size_t)blockIdx.y * 256) * PWORDS;
  for (int k = tid; k < 256 * PWORDS; k += 256) {
    const int a = k / PWORDS, w = k - a * PWORDS;
    gbase[k] = cnt[(2 * w) * 256 + a] | (cnt[(2 * w + 1) * 256 + a] << 16);
  }
}

// ---------------------------------------------------------------------------
// k2: reduce NCHUNK packed partials (u32 adds; u16 halves can't carry since
// totals <= 8191), unpack to LDS, then out = occ @ W^T + b.
// 512 blocks x 256 thr; 16 agents/block; thread = (agent, 8 h's).
// W in LDS (144B rows: float4-aligned, <=2-way banks). Reduce loop is
// compile-time unrolled -> 32 independent loads in flight (BW-bound, ~19 MB).
// ---------------------------------------------------------------------------
__global__ __launch_bounds__(256) void occ_gemm_kernel(
    const unsigned* __restrict__ partial, const float* __restrict__ W,
    const float* __restrict__ bias, float* __restrict__ out) {
  __shared__ float Wl[HIDDEN * NCELL];
  __shared__ float occ[16 * CSTRIDE];
  const int tid = threadIdx.x;

  const float4* W4 = (const float4*)W;
  float4* Wl4 = (float4*)Wl;
  for (int k = tid; k < HIDDEN * NCELL / 4; k += 256) Wl4[k] = W4[k];

  const int agBase = blockIdx.x * 16;
  for (int k = tid; k < 16 * PWORDS; k += 256) {
    const int a = k / PWORDS, w = k - a * PWORDS;
    const unsigned* p = partial + (size_t)(agBase + a) * PWORDS + w;
    unsigned s = 0;
#pragma unroll
    for (int c = 0; c < NCHUNK; ++c) s += p[(size_t)c * NAGENT * PWORDS];
    occ[a * CSTRIDE + 2 * w]     = (float)(s & 0xFFFFu);
    occ[a * CSTRIDE + 2 * w + 1] = (float)(s >> 16);
  }
  __syncthreads();

  const int a  = tid >> 4;
  const int hg = tid & 15;

  float occf[NCELL];
#pragma unroll
  for (int c = 0; c < NCELL; ++c) occf[c] = occ[a * CSTRIDE + c];

  float acc[8];
#pragma unroll
  for (int k = 0; k < 8; ++k) acc[k] = bias[hg + 16 * k];

#pragma unroll
  for (int c4 = 0; c4 < 9; ++c4) {
#pragma unroll
    for (int k = 0; k < 8; ++k) {
      const float4 w4 = *(const float4*)&Wl[(hg + 16 * k) * NCELL + c4 * 4];
      acc[k] = fmaf(occf[4 * c4 + 0], w4.x, acc[k]);
      acc[k] = fmaf(occf[4 * c4 + 1], w4.y, acc[k]);
      acc[k] = fmaf(occf[4 * c4 + 2], w4.z, acc[k]);
      acc[k] = fmaf(occf[4 * c4 + 3], w4.w, acc[k]);
    }
  }

  float* ob = out + (size_t)(agBase + a) * HIDDEN;
#pragma unroll
  for (int k = 0; k < 8; ++k) ob[hg + 16 * k] = acc[k];
}

extern "C" void kernel_launch(void* const* d_in, const int* in_sizes, int n_in,
                              void* d_out, int out_size, void* d_ws, size_t ws_size,
                              hipStream_t stream) {
  (void)in_sizes; (void)n_in; (void)out_size; (void)ws_size;
  const float2* obs = (const float2*)d_in[0];
  const float*  W   = (const float*)d_in[1];
  const float*  b   = (const float*)d_in[2];
  float* out = (float*)d_out;
  unsigned* partial = (unsigned*)d_ws;  // 32*8192*18*4 = 18.9 MB of workspace

  occ_hist_kernel<<<dim3(NCHUNK, 32), dim3(256), 0, stream>>>(obs, partial);
  occ_gemm_kernel<<<dim3(512), dim3(256), 0, stream>>>(partial, W, b, out);
}

// Round 5
// 99.724 us; speedup vs baseline: 1.0762x; 1.0762x over previous
//
#include <hip/hip_runtime.h>

#define NAGENT 8192
#define NCELL 36
#define HIDDEN 128
#define CSTRIDE 37    // k2 LDS occ row stride (gcd(37,32)=1)
#define PWORDS 18     // 36 cells packed as 18 u32 (2 x u16)
#define ROWS 19       // 18 packed rows + 1 dummy row for invalid points
#define NCHUNK 16
#define JCHUNK (NAGENT / NCHUNK)  // 512 js per block, 128 per wave

// ---------------------------------------------------------------------------
// k1: pairwise occupancy histogram. Grid dim3(NCHUNK, 128) = 2048 blocks ->
// 8 blocks/CU x 4 waves = 32 waves/CU (R4's regression was occupancy: 1024
// blocks @ 36.9KB LDS = 16 waves/CU). Block = 64 agents (lane = agent);
// the 4 waves split the j-chunk 4 ways (128 js each).
// Counters: col-major PACKED 2xu16 -> cnt[(cell>>1)*64 + lane], add 1 or
// 0x10000 (per-chunk counts <= 512: no carry). Bank = lane%32 for every row
// -> guaranteed 2-way = free. LDS only 4.9 KB.
// BRANCHLESS hot loop: invalid/self points are cndmask'd to dummy row 18 and
// ds_add'd unconditionally -- no exec-mask branches (R4's predicated atomic
// cost ~4 SALU + 2 branches per point). Classification via v_cvt_flr
// ((int)floorf) + 2 unsigned compares instead of 4 float compares.
// NOTE: relies on NaN-free obs (setup_inputs is randn; cvt(NaN)=0 would
// land in cell 0 -- float-compare version would be needed if NaNs possible).
// Epilogue: packed words stored directly, coalesced, layout [chunk][w][agent].
// ---------------------------------------------------------------------------
__global__ __launch_bounds__(256) void occ_hist_kernel(
    const float2* __restrict__ obs, unsigned* __restrict__ partial) {
  __shared__ unsigned cnt[ROWS * 64];  // 4864 B
  const int tid  = threadIdx.x;
  const int lane = tid & 63;
  const int wv   = tid >> 6;

  for (int k = tid; k < ROWS * 64; k += 256) cnt[k] = 0u;
  __syncthreads();

  const int agent = blockIdx.y * 64 + lane;
  const float2 oi = obs[agent];
  const float cx = fmaf(oi.x, -2.0f, 3.0f);  // rx = xj*2 + (3 - 2*xi)
  const float cy = fmaf(oi.y, -2.0f, 3.0f);
  unsigned* myCol = &cnt[lane];

  const int jbeg = blockIdx.x * JCHUNK + wv * (JCHUNK / 4);
  const float4* jp = (const float4*)obs + (jbeg >> 1);

#pragma unroll 8
  for (int t = 0; t < JCHUNK / 8; ++t) {
    const float4 o2 = jp[t];  // wave-uniform addr -> broadcast load
    const int j0 = jbeg + 2 * t;
    {
      const float rx = fmaf(o2.x, 2.0f, cx);
      const float ry = fmaf(o2.y, 2.0f, cy);
      const int ux = (int)__builtin_floorf(rx);   // v_cvt_flr_i32_f32
      const int uy = (int)__builtin_floorf(ry);
      const bool valid = ((unsigned)ux < 6u) & ((unsigned)uy < 6u) & (agent != j0);
      const int cell = ux * 6 + uy;
      const int row = valid ? (cell >> 1) : (ROWS - 1);   // cndmask, no branch
      const unsigned val = 1u + (unsigned)(cell & 1) * 65535u;  // 1 | 0x10000
      atomicAdd(&myCol[row * 64], val);  // unconditional ds_add, 2-way banks
    }
    {
      const float rx = fmaf(o2.z, 2.0f, cx);
      const float ry = fmaf(o2.w, 2.0f, cy);
      const int ux = (int)__builtin_floorf(rx);
      const int uy = (int)__builtin_floorf(ry);
      const bool valid = ((unsigned)ux < 6u) & ((unsigned)uy < 6u) & (agent != j0 + 1);
      const int cell = ux * 6 + uy;
      const int row = valid ? (cell >> 1) : (ROWS - 1);
      const unsigned val = 1u + (unsigned)(cell & 1) * 65535u;
      atomicAdd(&myCol[row * 64], val);
    }
  }
  __syncthreads();

  // store packed partials, layout [chunk][w][agent]; cnt[w*64+l] read is
  // bank l%32 (2-way, free); stores perfectly coalesced (64 x 4B runs).
  unsigned* gbase = partial + (size_t)blockIdx.x * PWORDS * NAGENT +
                    (size_t)blockIdx.y * 64;
  for (int k = tid; k < PWORDS * 64; k += 256) {
    const int w = k >> 6, l = k & 63;
    gbase[(size_t)w * NAGENT + l] = cnt[w * 64 + l];
  }
}

// ---------------------------------------------------------------------------
// k2: reduce NCHUNK packed partials (u32 adds; u16 halves can't carry since
// totals <= 8191), unpack to LDS, then out = occ @ W^T + b.
// 512 blocks x 256 thr; 16 agents/block; thread = (agent, 8 h's).
// Reduce index map: a = k&15 (minor) -> 16 consecutive u32 per (w,c) = 64B
// coalesced segments. Reduce loop compile-time unrolled (16 loads in flight).
// W in LDS (144B rows: float4-aligned, <=2-way banks).
// ---------------------------------------------------------------------------
__global__ __launch_bounds__(256) void occ_gemm_kernel(
    const unsigned* __restrict__ partial, const float* __restrict__ W,
    const float* __restrict__ bias, float* __restrict__ out) {
  __shared__ float Wl[HIDDEN * NCELL];
  __shared__ float occ[16 * CSTRIDE];
  const int tid = threadIdx.x;

  const float4* W4 = (const float4*)W;
  float4* Wl4 = (float4*)Wl;
  for (int k = tid; k < HIDDEN * NCELL / 4; k += 256) Wl4[k] = W4[k];

  const int agBase = blockIdx.x * 16;
  for (int k = tid; k < 16 * PWORDS; k += 256) {
    const int a = k & 15, w = k >> 4;
    const unsigned* p = partial + (size_t)w * NAGENT + agBase + a;
    unsigned s = 0;
#pragma unroll
    for (int c = 0; c < NCHUNK; ++c) s += p[(size_t)c * PWORDS * NAGENT];
    occ[a * CSTRIDE + 2 * w]     = (float)(s & 0xFFFFu);
    occ[a * CSTRIDE + 2 * w + 1] = (float)(s >> 16);
  }
  __syncthreads();

  const int a  = tid >> 4;
  const int hg = tid & 15;

  float occf[NCELL];
#pragma unroll
  for (int c = 0; c < NCELL; ++c) occf[c] = occ[a * CSTRIDE + c];

  float acc[8];
#pragma unroll
  for (int k = 0; k < 8; ++k) acc[k] = bias[hg + 16 * k];

#pragma unroll
  for (int c4 = 0; c4 < 9; ++c4) {
#pragma unroll
    for (int k = 0; k < 8; ++k) {
      const float4 w4 = *(const float4*)&Wl[(hg + 16 * k) * NCELL + c4 * 4];
      acc[k] = fmaf(occf[4 * c4 + 0], w4.x, acc[k]);
      acc[k] = fmaf(occf[4 * c4 + 1], w4.y, acc[k]);
      acc[k] = fmaf(occf[4 * c4 + 2], w4.z, acc[k]);
      acc[k] = fmaf(occf[4 * c4 + 3], w4.w, acc[k]);
    }
  }

  float* ob = out + (size_t)(agBase + a) * HIDDEN;
#pragma unroll
  for (int k = 0; k < 8; ++k) ob[hg + 16 * k] = acc[k];
}

extern "C" void kernel_launch(void* const* d_in, const int* in_sizes, int n_in,
                              void* d_out, int out_size, void* d_ws, size_t ws_size,
                              hipStream_t stream) {
  (void)in_sizes; (void)n_in; (void)out_size; (void)ws_size;
  const float2* obs = (const float2*)d_in[0];
  const float*  W   = (const float*)d_in[1];
  const float*  b   = (const float*)d_in[2];
  float* out = (float*)d_out;
  unsigned* partial = (unsigned*)d_ws;  // 16*18*8192*4 = 9.4 MB of workspace

  occ_hist_kernel<<<dim3(NCHUNK, 128), dim3(256), 0, stream>>>(obs, partial);
  occ_gemm_kernel<<<dim3(512), dim3(256), 0, stream>>>(partial, W, b, out);
}

// Round 6
// 97.228 us; speedup vs baseline: 1.1038x; 1.0257x over previous
//
#include <hip/hip_runtime.h>

#define NAGENT 8192
#define NCELL 36
#define HIDDEN 128
#define CSTRIDE 37    // k2 LDS occ row stride (gcd(37,32)=1)
#define PWORDS 18     // 36 cells packed as 18 u32 (2 x u16)
#define NCHUNK 16
#define JCHUNK (NAGENT / NCHUNK)  // 512 js per block, 128 per wave

// ---------------------------------------------------------------------------
// k1: pairwise occupancy histogram. Grid dim3(NCHUNK, 128) = 2048 blocks ->
// 8 blocks/CU x 4 waves = 32 waves/CU. Block = 64 agents (lane = agent);
// 4 waves split the j-chunk 4 ways (128 js each, global float4 broadcasts).
//
// R6 combines the proven-good pieces of R3+R5 and drops the proven-bad ones:
//  - PREDICATED atomic (R3): only ~50% of pairs are valid -> 0.5 LDS atomics
//    per point. R5's branchless dummy-row trick doubled atomic traffic and
//    the LDS atomic pipe (~12 cyc/wave-atomic: 2 bank passes x RMW, per-CU)
//    was the bottleneck -> regression.
//  - Col-major PACKED u16 counters (R5): cnt[(cell>>1)*64 + lane], add
//    1 or 1<<16 (per-chunk counts <= 512: no carry). Bank = lane%32 for every
//    row -> guaranteed 2-pass, never the ~3+ of R3's row-major layout.
//  - No LDS reads in hot loop (R5): j loads are wave-uniform global float4
//    broadcasts; R3's ds_read_b128 stream fought the atomics for the pipe.
//  - No cndmask row/val machinery (-3 VALU/pt vs R5).
// VALU ~13/pt (~10.5 us floor) ~= LDS pipe 0.5*12cyc/pt (~10 us) -> balanced.
// NOTE: relies on NaN-free obs (setup_inputs is randn; cvt(NaN)=0 would land
// in cell 0 -- float-compare version needed if NaNs were possible).
// ---------------------------------------------------------------------------
__global__ __launch_bounds__(256) void occ_hist_kernel(
    const float2* __restrict__ obs, unsigned* __restrict__ partial) {
  __shared__ unsigned cnt[PWORDS * 64];  // 4608 B
  const int tid  = threadIdx.x;
  const int lane = tid & 63;
  const int wv   = tid >> 6;

  for (int k = tid; k < PWORDS * 64; k += 256) cnt[k] = 0u;
  __syncthreads();

  const int agent = blockIdx.y * 64 + lane;
  const float2 oi = obs[agent];
  const float cx = fmaf(oi.x, -2.0f, 3.0f);  // rx = xj*2 + (3 - 2*xi)
  const float cy = fmaf(oi.y, -2.0f, 3.0f);
  unsigned* myCol = &cnt[lane];

  const int jbeg = blockIdx.x * JCHUNK + wv * (JCHUNK / 4);
  const float4* jp = (const float4*)obs + (jbeg >> 1);

#pragma unroll 8
  for (int t = 0; t < JCHUNK / 8; ++t) {
    const float4 o2 = jp[t];  // wave-uniform addr -> broadcast load
    const int j0 = jbeg + 2 * t;
    {
      const float rx = fmaf(o2.x, 2.0f, cx);
      const float ry = fmaf(o2.y, 2.0f, cy);
      const int ux = (int)__builtin_floorf(rx);   // v_cvt_flr_i32_f32
      const int uy = (int)__builtin_floorf(ry);
      const int cell = ux * 6 + uy;
      const unsigned val = 1u << ((cell & 1) << 4);  // 1 | 0x10000
      if (((unsigned)ux < 6u) & ((unsigned)uy < 6u) & (agent != j0))
        atomicAdd(&myCol[(cell >> 1) << 6], val);  // exec-masked ds_add
    }
    {
      const float rx = fmaf(o2.z, 2.0f, cx);
      const float ry = fmaf(o2.w, 2.0f, cy);
      const int ux = (int)__builtin_floorf(rx);
      const int uy = (int)__builtin_floorf(ry);
      const int cell = ux * 6 + uy;
      const unsigned val = 1u << ((cell & 1) << 4);
      if (((unsigned)ux < 6u) & ((unsigned)uy < 6u) & (agent != j0 + 1))
        atomicAdd(&myCol[(cell >> 1) << 6], val);
    }
  }
  __syncthreads();

  // store packed partials, layout [chunk][w][agent]; cnt[w*64+l] read is
  // bank l%32 (2-way, free); stores perfectly coalesced (64 x 4B runs).
  unsigned* gbase = partial + (size_t)blockIdx.x * PWORDS * NAGENT +
                    (size_t)blockIdx.y * 64;
  for (int k = tid; k < PWORDS * 64; k += 256) {
    const int w = k >> 6, l = k & 63;
    gbase[(size_t)w * NAGENT + l] = cnt[w * 64 + l];
  }
}

// ---------------------------------------------------------------------------
// k2: reduce NCHUNK packed partials (u32 adds; u16 halves can't carry since
// totals <= 8191), unpack to LDS, then out = occ @ W^T + b.
// 512 blocks x 256 thr; 16 agents/block; thread = (agent, 8 h's).
// Reduce loop compile-time unrolled (16 loads in flight, ~9.4 MB coalesced).
// W in LDS (144B rows: float4-aligned, <=2-way banks).
// ---------------------------------------------------------------------------
__global__ __launch_bounds__(256) void occ_gemm_kernel(
    const unsigned* __restrict__ partial, const float* __restrict__ W,
    const float* __restrict__ bias, float* __restrict__ out) {
  __shared__ float Wl[HIDDEN * NCELL];
  __shared__ float occ[16 * CSTRIDE];
  const int tid = threadIdx.x;

  const float4* W4 = (const float4*)W;
  float4* Wl4 = (float4*)Wl;
  for (int k = tid; k < HIDDEN * NCELL / 4; k += 256) Wl4[k] = W4[k];

  const int agBase = blockIdx.x * 16;
  for (int k = tid; k < 16 * PWORDS; k += 256) {
    const int a = k & 15, w = k >> 4;
    const unsigned* p = partial + (size_t)w * NAGENT + agBase + a;
    unsigned s = 0;
#pragma unroll
    for (int c = 0; c < NCHUNK; ++c) s += p[(size_t)c * PWORDS * NAGENT];
    occ[a * CSTRIDE + 2 * w]     = (float)(s & 0xFFFFu);
    occ[a * CSTRIDE + 2 * w + 1] = (float)(s >> 16);
  }
  __syncthreads();

  const int a  = tid >> 4;
  const int hg = tid & 15;

  float occf[NCELL];
#pragma unroll
  for (int c = 0; c < NCELL; ++c) occf[c] = occ[a * CSTRIDE + c];

  float acc[8];
#pragma unroll
  for (int k = 0; k < 8; ++k) acc[k] = bias[hg + 16 * k];

#pragma unroll
  for (int c4 = 0; c4 < 9; ++c4) {
#pragma unroll
    for (int k = 0; k < 8; ++k) {
      const float4 w4 = *(const float4*)&Wl[(hg + 16 * k) * NCELL + c4 * 4];
      acc[k] = fmaf(occf[4 * c4 + 0], w4.x, acc[k]);
      acc[k] = fmaf(occf[4 * c4 + 1], w4.y, acc[k]);
      acc[k] = fmaf(occf[4 * c4 + 2], w4.z, acc[k]);
      acc[k] = fmaf(occf[4 * c4 + 3], w4.w, acc[k]);
    }
  }

  float* ob = out + (size_t)(agBase + a) * HIDDEN;
#pragma unroll
  for (int k = 0; k < 8; ++k) ob[hg + 16 * k] = acc[k];
}

extern "C" void kernel_launch(void* const* d_in, const int* in_sizes, int n_in,
                              void* d_out, int out_size, void* d_ws, size_t ws_size,
                              hipStream_t stream) {
  (void)in_sizes; (void)n_in; (void)out_size; (void)ws_size;
  const float2* obs = (const float2*)d_in[0];
  const float*  W   = (const float*)d_in[1];
  const float*  b   = (const float*)d_in[2];
  float* out = (float*)d_out;
  unsigned* partial = (unsigned*)d_ws;  // 16*18*8192*4 = 9.4 MB of workspace

  occ_hist_kernel<<<dim3(NCHUNK, 128), dim3(256), 0, stream>>>(obs, partial);
  occ_gemm_kernel<<<dim3(512), dim3(256), 0, stream>>>(partial, W, b, out);
}

// Round 7
// 88.952 us; speedup vs baseline: 1.2065x; 1.0930x over previous
//
#include <hip/hip_runtime.h>

#define NAGENT 8192
#define NCELL 36
#define HIDDEN 128
#define CSTRIDE 37    // k2 LDS occ row stride (gcd(37,32)=1)
#define PWORDS 18     // 36 cells packed as 18 u32 (2 x u16)
#define NROWS 64      // 8x8 clamp grid: border rows absorb out-of-range points
#define NCHUNK 16
#define JCHUNK (NAGENT / NCHUNK)  // 512 js per block, 128 per wave

// ---------------------------------------------------------------------------
// k1: pairwise occupancy histogram. Grid dim3(NCHUNK, 128) = 2048 blocks ->
// 8 blocks/CU x 4 waves = 32 waves/CU. Block = 64 agents (lane = agent);
// 4 waves split the j-chunk 4 ways (128 js each, global float4 broadcasts).
//
// R7: k1 is VALU-ISSUE-bound (R5-vs-R6 calibration: 1 op/pt ~ 0.85 us; the
// LDS atomic issues ~1/pt regardless of predication since any-lane-active).
// So: MINIMUM ops/pt, branchless via CLAMP instead of compare+predicate:
//   ux = med3(cvt_flr(fmaf(dx,2,3)), -1, 6)  per coord
// -> out-of-range points land in border rows of an 8x8=64-row counter grid;
// only the interior 6x6 is harvested in the epilogue. No compares, no
// saveexec/branch, no packed-val computation (u32 counters, add constant 1).
// Per point: 2 sub + 2 fma + 2 cvt_flr + 2 med3 + 2 lshl_add + 1 ds_add
// = 10 VALU (was ~21).
// fmaf(xj-xi, 2, 3) is BIT-EXACT vs the reference ((oj-oi)/0.5 + 3): 2*dx is
// exact, one rounding -> boundary classification matches numpy, and the self
// pair (dx=0) lands exactly at row (4,4) (= cell (3,3)), subtracted in k2.
// Counters col-major cnt[row*64+lane]: bank = lane%32 -> 2-way = free (m136).
// NOTE: relies on NaN-free obs (setup_inputs is randn); cvt(NaN)=0 would land
// in a valid row -- the reference would discard it.
// ---------------------------------------------------------------------------
__global__ __launch_bounds__(256) void occ_hist_kernel(
    const float2* __restrict__ obs, unsigned* __restrict__ partial) {
  __shared__ unsigned cnt[NROWS * 64];  // 16 KB -> 8 blocks/CU
  const int tid  = threadIdx.x;
  const int lane = tid & 63;
  const int wv   = tid >> 6;

#pragma unroll
  for (int k = tid; k < NROWS * 64; k += 256) cnt[k] = 0u;
  __syncthreads();

  const int agent = blockIdx.y * 64 + lane;
  const float2 oi = obs[agent];
  const float xi = oi.x, yi = oi.y;
  // row(v) for v = ux*8+uy, ux,uy in [-1,6] -> v in [-9,54]; +9 folded here:
  unsigned* base = cnt + 9 * 64 + lane;

  const int jbeg = blockIdx.x * JCHUNK + wv * (JCHUNK / 4);
  const float4* jp = (const float4*)obs + (jbeg >> 1);

#pragma unroll 8
  for (int t = 0; t < JCHUNK / 8; ++t) {
    const float4 o2 = jp[t];  // wave-uniform addr -> broadcast load (vmcnt)
    {
      const float rx = fmaf(o2.x - xi, 2.0f, 3.0f);   // bit-exact vs ref
      const float ry = fmaf(o2.y - yi, 2.0f, 3.0f);
      int ux = (int)__builtin_floorf(rx);             // v_cvt_flr_i32_f32
      int uy = (int)__builtin_floorf(ry);
      ux = min(max(ux, -1), 6);                       // v_med3_i32
      uy = min(max(uy, -1), 6);
      atomicAdd(&base[(ux * 8 + uy) * 64], 1u);       // unconditional ds_add
    }
    {
      const float rx = fmaf(o2.z - xi, 2.0f, 3.0f);
      const float ry = fmaf(o2.w - yi, 2.0f, 3.0f);
      int ux = (int)__builtin_floorf(rx);
      int uy = (int)__builtin_floorf(ry);
      ux = min(max(ux, -1), 6);
      uy = min(max(uy, -1), 6);
      atomicAdd(&base[(ux * 8 + uy) * 64], 1u);
    }
  }
  __syncthreads();

  // harvest interior 6x6 rows -> 18 packed u16 words (per-chunk counts<=513),
  // layout [chunk][w][agent]; LDS reads 2-way banks, stores coalesced 256B.
  unsigned* gbase = partial + (size_t)blockIdx.x * PWORDS * NAGENT +
                    (size_t)blockIdx.y * 64;
  for (int k = tid; k < PWORDS * 64; k += 256) {
    const int w = k >> 6, l = k & 63;
    const int c0 = 2 * w, c1 = 2 * w + 1;
    const int r0 = (c0 / 6 + 1) * 8 + (c0 % 6 + 1);
    const int r1 = (c1 / 6 + 1) * 8 + (c1 % 6 + 1);
    gbase[(size_t)w * NAGENT + l] = cnt[r0 * 64 + l] | (cnt[r1 * 64 + l] << 16);
  }
}

// ---------------------------------------------------------------------------
// k2: reduce NCHUNK packed partials (u32 adds; u16 halves can't carry since
// totals <= 8192), unpack to LDS, subtract the self-pair (cell 21 = word 10
// hi; always >= 1 since the self j is always counted), then occ @ W^T + b.
// 512 blocks x 256 thr; 16 agents/block; thread = (agent, 8 h's).
// Reduce loop compile-time unrolled (16 loads in flight, ~9.4 MB coalesced).
// W in LDS (144B rows: float4-aligned, <=2-way banks).
// ---------------------------------------------------------------------------
__global__ __launch_bounds__(256) void occ_gemm_kernel(
    const unsigned* __restrict__ partial, const float* __restrict__ W,
    const float* __restrict__ bias, float* __restrict__ out) {
  __shared__ float Wl[HIDDEN * NCELL];
  __shared__ float occ[16 * CSTRIDE];
  const int tid = threadIdx.x;

  const float4* W4 = (const float4*)W;
  float4* Wl4 = (float4*)Wl;
  for (int k = tid; k < HIDDEN * NCELL / 4; k += 256) Wl4[k] = W4[k];

  const int agBase = blockIdx.x * 16;
  for (int k = tid; k < 16 * PWORDS; k += 256) {
    const int a = k & 15, w = k >> 4;
    const unsigned* p = partial + (size_t)w * NAGENT + agBase + a;
    unsigned s = 0;
#pragma unroll
    for (int c = 0; c < NCHUNK; ++c) s += p[(size_t)c * PWORDS * NAGENT];
    float lo = (float)(s & 0xFFFFu);
    float hi = (float)(s >> 16);
    if (w == 10) hi -= 1.0f;  // cell 21: remove the always-counted self-pair
    occ[a * CSTRIDE + 2 * w]     = lo;
    occ[a * CSTRIDE + 2 * w + 1] = hi;
  }
  __syncthreads();

  const int a  = tid >> 4;
  const int hg = tid & 15;

  float occf[NCELL];
#pragma unroll
  for (int c = 0; c < NCELL; ++c) occf[c] = occ[a * CSTRIDE + c];

  float acc[8];
#pragma unroll
  for (int k = 0; k < 8; ++k) acc[k] = bias[hg + 16 * k];

#pragma unroll
  for (int c4 = 0; c4 < 9; ++c4) {
#pragma unroll
    for (int k = 0; k < 8; ++k) {
      const float4 w4 = *(const float4*)&Wl[(hg + 16 * k) * NCELL + c4 * 4];
      acc[k] = fmaf(occf[4 * c4 + 0], w4.x, acc[k]);
      acc[k] = fmaf(occf[4 * c4 + 1], w4.y, acc[k]);
      acc[k] = fmaf(occf[4 * c4 + 2], w4.z, acc[k]);
      acc[k] = fmaf(occf[4 * c4 + 3], w4.w, acc[k]);
    }
  }

  float* ob = out + (size_t)(agBase + a) * HIDDEN;
#pragma unroll
  for (int k = 0; k < 8; ++k) ob[hg + 16 * k] = acc[k];
}

extern "C" void kernel_launch(void* const* d_in, const int* in_sizes, int n_in,
                              void* d_out, int out_size, void* d_ws, size_t ws_size,
                              hipStream_t stream) {
  (void)in_sizes; (void)n_in; (void)out_size; (void)ws_size;
  const float2* obs = (const float2*)d_in[0];
  const float*  W   = (const float*)d_in[1];
  const float*  b   = (const float*)d_in[2];
  float* out = (float*)d_out;
  unsigned* partial = (unsigned*)d_ws;  // 16*18*8192*4 = 9.4 MB of workspace

  occ_hist_kernel<<<dim3(NCHUNK, 128), dim3(256), 0, stream>>>(obs, partial);
  occ_gemm_kernel<<<dim3(512), dim3(256), 0, stream>>>(partial, W, b, out);
}